// Round 13
// baseline (198.953 us; speedup 1.0000x reference)
//
#include <hip/hip_runtime.h>
#include <math.h>

#define DEV __device__ __forceinline__

constexpr int IN   = 1024;   // input features (K)
constexpr int OUT  = 1024;   // output features (N)
constexpr int NC   = 8;      // GMM components
constexpr int MAXM = 96;     // max missing entries tracked per row (Poisson(20.5): P(>96) ~ 1e-40)

typedef __bf16 bf16x8 __attribute__((ext_vector_type(8)));
typedef float  f32x4  __attribute__((ext_vector_type(4)));
typedef float  f32x2  __attribute__((ext_vector_type(2)));
typedef unsigned short u16x8 __attribute__((ext_vector_type(8)));
typedef unsigned int u32;

union ABf { bf16x8 v; u32 d[4]; unsigned short s[8]; };

DEV unsigned short f2bf(float f) {   // RNE float->bf16, input guaranteed non-NaN
  union { float f; u32 u; } v; v.f = f;
  u32 u = v.u;
  return (unsigned short)((u + 0x7FFFu + ((u >> 16) & 1u)) >> 16);
}

DEV void gload_lds16(const void* g, void* l) {
  __builtin_amdgcn_global_load_lds(
      (__attribute__((address_space(1))) void*)(unsigned long long)(uintptr_t)g,
      (__attribute__((address_space(3))) void*)l,
      16, 0, 0);
}

// ---------------------------------------------------------------------------
// K1: per-row NaN scan. Writes bf16 x_clean, deterministic (sorted) missing
// index list per row; pad slots zero-filled (k=0) so the epilogue's vector
// kv loads read benign indices (B-side zeroing makes them no-ops).
// ---------------------------------------------------------------------------
__global__ __launch_bounds__(256) void prep_kernel(
    const float* __restrict__ x, unsigned short* __restrict__ xb,
    unsigned short* __restrict__ midx, int* __restrict__ counts) {
  const int row = blockIdx.x, t = threadIdx.x;
  __shared__ int ps[256];

  float4 v = ((const float4*)x)[row * (IN / 4) + t];  // cols 4t..4t+3
  bool n0 = (v.x != v.x), n1 = (v.y != v.y), n2 = (v.z != v.z), n3 = (v.w != v.w);

  ushort4 o;
  o.x = f2bf(n0 ? 0.f : v.x);
  o.y = f2bf(n1 ? 0.f : v.y);
  o.z = f2bf(n2 ? 0.f : v.z);
  o.w = f2bf(n3 ? 0.f : v.w);
  ((ushort4*)xb)[row * (IN / 4) + t] = o;

  int lc = (int)n0 + (int)n1 + (int)n2 + (int)n3;
  ps[t] = lc;
  __syncthreads();
  for (int off = 1; off < 256; off <<= 1) {
    int add = (t >= off) ? ps[t - off] : 0;
    __syncthreads();
    ps[t] += add;
    __syncthreads();
  }
  int pos = ps[t] - lc;  // exclusive prefix
  int col = 4 * t;
  if (n0) { if (pos < MAXM) midx[row * MAXM + pos] = (unsigned short)(col + 0); pos++; }
  if (n1) { if (pos < MAXM) midx[row * MAXM + pos] = (unsigned short)(col + 1); pos++; }
  if (n2) { if (pos < MAXM) midx[row * MAXM + pos] = (unsigned short)(col + 2); pos++; }
  if (n3) { if (pos < MAXM) midx[row * MAXM + pos] = (unsigned short)(col + 3); pos++; }
  if (t == 255) counts[row] = min(ps[255], MAXM);
  __syncthreads();
  int mm = min(ps[255], MAXM);
  for (int idx = mm + t; idx < MAXM; idx += 256) midx[row * MAXM + idx] = 0;
}

// ---------------------------------------------------------------------------
// K1b: W [IN][OUT] f32 -> Wt [OUT][IN] bf16 (B^T layout for the MFMA GEMM).
// Block (0,0) additionally computes softmax(gw) -> p_ws[8] (row-independent).
// (R9 version: NO W16 shadow copy -- workspace stays in the proven footprint.)
// ---------------------------------------------------------------------------
__global__ __launch_bounds__(256) void transpose_w(
    const float* __restrict__ W, unsigned short* __restrict__ Wt,
    const float* __restrict__ gw, float* __restrict__ p_ws) {
  __shared__ float tile[32][33];
  const int k0 = blockIdx.x * 32, n0 = blockIdx.y * 32;
  const int tx = threadIdx.x, ty = threadIdx.y;

  if (k0 == 0 && n0 == 0 && tx == 0 && ty == 0) {
    float wmax = -1e30f;
    for (int i = 0; i < NC; ++i) wmax = fmaxf(wmax, gw[i]);
    float e[NC], s = 0.f;
    for (int i = 0; i < NC; ++i) { e[i] = expf(gw[i] - wmax); s += e[i]; }
    for (int i = 0; i < NC; ++i) p_ws[i] = e[i] / s;
  }

  for (int r = ty; r < 32; r += 8) tile[r][tx] = W[(k0 + r) * OUT + (n0 + tx)];
  __syncthreads();
  for (int r = ty; r < 32; r += 8) Wt[(n0 + r) * IN + (k0 + tx)] = f2bf(tile[tx][r]);
}

// ---------------------------------------------------------------------------
// K2: base = xb @ Wt^T. 128x128 tile, BK=32, 4 waves, global_load_lds
// staging (m97 structure). Unchanged since R1.
// ---------------------------------------------------------------------------
__global__ __launch_bounds__(256) void gemm_base(
    const unsigned short* __restrict__ A, const unsigned short* __restrict__ Bt,
    float* __restrict__ C, int M) {
  __shared__ __align__(16) unsigned short sA[128 * 32];
  __shared__ __align__(16) unsigned short sB[128 * 32];

  const int t = threadIdx.x;
  const int lane = t & 63, w = t >> 6;
  const int wm = w >> 1, wn = w & 1;
  const int l15 = lane & 15, kblk = lane >> 4;
  const int row0 = blockIdx.x * 128, col0 = blockIdx.y * 128;

  const int r_a  = t >> 2;
  const int cb_a = (t & 3) * 8;

  f32x4 acc[4][4] = {};

  const int aoff = (wm * 64 + l15) * 32 + kblk * 8;
  const int boff = (wn * 64 + l15) * 32 + kblk * 8;

  for (int k0 = 0; k0 < IN; k0 += 32) {
    __syncthreads();
    gload_lds16(&A[(size_t)(row0 + r_a) * IN + k0 + cb_a],       &sA[t * 8]);
    gload_lds16(&A[(size_t)(row0 + r_a + 64) * IN + k0 + cb_a],  &sA[2048 + t * 8]);
    gload_lds16(&Bt[(size_t)(col0 + r_a) * IN + k0 + cb_a],      &sB[t * 8]);
    gload_lds16(&Bt[(size_t)(col0 + r_a + 64) * IN + k0 + cb_a], &sB[2048 + t * 8]);
    __syncthreads();

    bf16x8 af[4], bfr[4];
#pragma unroll
    for (int mi = 0; mi < 4; ++mi) af[mi]  = *(const bf16x8*)&sA[aoff + mi * 16 * 32];
#pragma unroll
    for (int ni = 0; ni < 4; ++ni) bfr[ni] = *(const bf16x8*)&sB[boff + ni * 16 * 32];
#pragma unroll
    for (int mi = 0; mi < 4; ++mi)
#pragma unroll
      for (int ni = 0; ni < 4; ++ni)
        acc[mi][ni] = __builtin_amdgcn_mfma_f32_16x16x32_bf16(af[mi], bfr[ni], acc[mi][ni], 0, 0, 0);
  }

#pragma unroll
  for (int mi = 0; mi < 4; ++mi)
#pragma unroll
    for (int ni = 0; ni < 4; ++ni) {
      int grow = row0 + wm * 64 + mi * 16 + kblk * 4;
      int gcol = col0 + wn * 64 + ni * 16 + l15;
#pragma unroll
      for (int r = 0; r < 4; ++r)
        C[(size_t)(grow + r) * OUT + gcol] = acc[mi][ni][r];
    }
}

// ---------------------------------------------------------------------------
// K3 (MFMA v5 = R9's verified data path + R11's throughput structure, W16
// removed): Grid (M,2); 4 waves; wave owns 128 cols = 8 tiles of 16.
//   - A elems loaded from the f32 W INPUT (R9-proven) via 32-bit element
//     offsets (saddr-form loads, no 64-bit VALU addr math) + offset: imms
//   - 2-deep tile pipeline: tile t+1's 8 loads issued before packing tile t
//   - no LDS, no barriers: kv slots = one 16B load from zero-padded midx
//   - pack via v_cvt_pk_bf16_f32 (R9 numerics); 2 MFMAs/tile into AGPR acc
// nr()/shfl readout verbatim from R9 (passed, absmax 0.5).
// ---------------------------------------------------------------------------
__global__ __launch_bounds__(256) void epilogue_mfma5(
    float* __restrict__ io, const float* __restrict__ W,
    const float* __restrict__ bvec, const float* __restrict__ p_ws,
    const float* __restrict__ gmean, const float* __restrict__ gcov,
    const unsigned short* __restrict__ midx, const int* __restrict__ counts) {
  const int row = blockIdx.x;
  const int cb  = blockIdx.y * 512;
  const int t   = threadIdx.x;
  const int lane = t & 63, wvi = t >> 6;
  const int nn = lane & 15, ii = lane & 7, g = lane >> 4;
  const bool isCov = nn >= 8;

  const int m = counts[row];

  if (m == 0) {  // full row: relu (uniform; essentially never taken at 2% miss)
    int c = cb + 2 * t;
    f32x2 bb = *(const f32x2*)(io + (size_t)row * OUT + c);
    f32x2 bi = *(const f32x2*)(bvec + c);
    f32x2 r; r[0] = fmaxf(bb[0] + bi[0], 0.f); r[1] = fmaxf(bb[1] + bi[1], 0.f);
    *(f32x2*)(io + (size_t)row * OUT + c) = r;
    return;
  }

  const int nch = (m + 31) >> 5;
  const unsigned short* mrow = midx + (size_t)row * MAXM;

  const unsigned colA = (unsigned)(cb + wvi * 128 + nn);  // lane's col (+16/tile)
  const float* gsrc = (isCov ? gcov : gmean) + ii * IN;   // comp source row

  f32x4 acc[8] = {};

  for (int ch = 0; ch < nch; ++ch) {
    // lane's 8 k-slots: one 16B load (pad region zero-filled by prep)
    u16x8 kvv = *(const u16x8*)&mrow[ch * 32 + g * 8];

    unsigned aoff[8];
#pragma unroll
    for (int j = 0; j < 8; ++j) aoff[j] = ((unsigned)kvv[j] << 10) + colA;

    // ---- B fragment: (mean | |cov|) for comp ii, slots g*8..g*8+7 ----
    float bv[8];
#pragma unroll
    for (int j = 0; j < 8; ++j) {
      float v = gsrc[kvv[j]];
      if (isCov) v = fabsf(v);
      bv[j] = (ch * 32 + g * 8 + j < m) ? v : 0.f;       // zero padded slots
    }
    ABf vals;
#pragma unroll
    for (int j = 0; j < 4; ++j)
      asm("v_cvt_pk_bf16_f32 %0, %1, %2" : "=v"(vals.d[j]) : "v"(bv[2*j]), "v"(bv[2*j+1]));
    ABf zf; zf.d[0] = zf.d[1] = zf.d[2] = zf.d[3] = 0;
    bf16x8 bm = isCov ? zf.v : vals.v;   // mean half (N-cols 0..7)
    bf16x8 bc = isCov ? vals.v : zf.v;   // cov  half (N-cols 8..15)

    // ---- A pipeline: 8 col-tiles, 2-deep (tile t+1 loads in flight) ----
    float curv[8], nxtv[8];
#pragma unroll
    for (int j = 0; j < 8; ++j) curv[j] = W[aoff[j]];            // tile 0
#pragma unroll
    for (int tl = 0; tl < 8; ++tl) {
      if (tl < 7) {
#pragma unroll
        for (int j = 0; j < 8; ++j) nxtv[j] = W[aoff[j] + (tl + 1) * 16];
      }
      ABf aw, a2;
#pragma unroll
      for (int p = 0; p < 4; ++p) {
        asm("v_cvt_pk_bf16_f32 %0, %1, %2" : "=v"(aw.d[p]) : "v"(curv[2*p]), "v"(curv[2*p+1]));
        float q0 = curv[2*p] * curv[2*p], q1 = curv[2*p+1] * curv[2*p+1];
        asm("v_cvt_pk_bf16_f32 %0, %1, %2" : "=v"(a2.d[p]) : "v"(q0), "v"(q1));
      }
      acc[tl] = __builtin_amdgcn_mfma_f32_16x16x32_bf16(aw.v, bm, acc[tl], 0, 0, 0);
      acc[tl] = __builtin_amdgcn_mfma_f32_16x16x32_bf16(a2.v, bc, acc[tl], 0, 0, 0);
#pragma unroll
      for (int j = 0; j < 8; ++j) curv[j] = nxtv[j];
    }
  }

  // ---- nr() epilogue (R9-verified readout) ----
  const float INV_SQRT_2PI = 0.39894228040143268f;
  const float LOGI_K = 1.702f;
  const float L2E = 1.442695040888963f;
  const float pi_w = p_ws[ii];
  const int rrb = isCov ? 2 : 0;

#pragma unroll
  for (int tl = 0; tl < 8; ++tl) {
    f32x4 ac = acc[tl];
    float s0 = __shfl_xor(ac[0], 8);
    float s1 = __shfl_xor(ac[1], 8);
    float s2 = __shfl_xor(ac[2], 8);
    float s3 = __shfl_xor(ac[3], 8);
    float A0 = isCov ? s2 : ac[0];
    float A1 = isCov ? s3 : ac[1];
    float V0 = isCov ? ac[2] : s0;
    float V1 = isCov ? ac[3] : s1;

    int c = cb + wvi * 128 + tl * 16 + g * 4 + rrb;
    f32x2 bb = *(const f32x2*)(io + (size_t)row * OUT + c);
    f32x2 bi = *(const f32x2*)(bvec + c);

    float t0, t1;
    {
      float a   = bb[0] + bi[0] + A0;
      float rs  = (V0 > 0.f) ? __builtin_amdgcn_rsqf(V0) : 1.0f;
      float z   = a * rs;
      float eu  = __builtin_amdgcn_exp2f(-0.5f * L2E * z * z);
      float el  = __builtin_amdgcn_exp2f(-LOGI_K * L2E * z);
      float Phi = __builtin_amdgcn_rcpf(1.0f + el);
      t0 = pi_w * fmaf(z, Phi, INV_SQRT_2PI * eu);
    }
    {
      float a   = bb[1] + bi[1] + A1;
      float rs  = (V1 > 0.f) ? __builtin_amdgcn_rsqf(V1) : 1.0f;
      float z   = a * rs;
      float eu  = __builtin_amdgcn_exp2f(-0.5f * L2E * z * z);
      float el  = __builtin_amdgcn_exp2f(-LOGI_K * L2E * z);
      float Phi = __builtin_amdgcn_rcpf(1.0f + el);
      t1 = pi_w * fmaf(z, Phi, INV_SQRT_2PI * eu);
    }
#pragma unroll
    for (int d = 1; d <= 4; d <<= 1) {
      t0 += __shfl_xor(t0, d);
      t1 += __shfl_xor(t1, d);
    }
    if (ii == 0) {
      f32x2 o; o[0] = t0; o[1] = t1;
      *(f32x2*)(io + (size_t)row * OUT + c) = o;
    }
  }
}

// ---------------------------------------------------------------------------
extern "C" void kernel_launch(void* const* d_in, const int* in_sizes, int n_in,
                              void* d_out, int out_size, void* d_ws, size_t ws_size,
                              hipStream_t stream) {
  const float* x  = (const float*)d_in[0];
  const float* W  = (const float*)d_in[1];
  const float* b  = (const float*)d_in[2];
  const float* gw = (const float*)d_in[3];
  const float* gm = (const float*)d_in[4];
  const float* gc = (const float*)d_in[5];
  float* out = (float*)d_out;
  const int M = in_sizes[0] / IN;  // 8192

  // workspace layout (R9-proven footprint, ~19.5 MB; no W16 shadow copy)
  char* ws = (char*)d_ws;
  size_t off = 0;
  unsigned short* xb   = (unsigned short*)(ws + off); off += (size_t)M * IN * 2;     // 16 MB
  unsigned short* Wt   = (unsigned short*)(ws + off); off += (size_t)IN * OUT * 2;   //  2 MB
  unsigned short* midx = (unsigned short*)(ws + off); off += (size_t)M * MAXM * 2;   // 1.5 MB
  int* counts          = (int*)(ws + off);            off += (size_t)M * 4;          // 32 KB
  float* p_ws          = (float*)(ws + off);          off += 256;

  prep_kernel<<<M, 256, 0, stream>>>(x, xb, midx, counts);
  transpose_w<<<dim3(IN / 32, OUT / 32), dim3(32, 8), 0, stream>>>(W, Wt, gw, p_ws);
  gemm_base<<<dim3(M / 128, OUT / 128), 256, 0, stream>>>(xb, Wt, out, M);
  epilogue_mfma5<<<dim3(M, 2), 256, 0, stream>>>(out, W, b, p_ws, gm, gc, midx, counts);
}

// Round 14
// 198.253 us; speedup vs baseline: 1.0035x; 1.0035x over previous
//
#include <hip/hip_runtime.h>
#include <math.h>

#define DEV __device__ __forceinline__

constexpr int IN   = 1024;   // input features (K)
constexpr int OUT  = 1024;   // output features (N)
constexpr int NC   = 8;      // GMM components
constexpr int MAXM = 96;     // max missing entries tracked per row (Poisson(20.5): P(>96) ~ 1e-40)

typedef __bf16 bf16x8 __attribute__((ext_vector_type(8)));
typedef float  f32x4  __attribute__((ext_vector_type(4)));
typedef float  f32x2  __attribute__((ext_vector_type(2)));
typedef unsigned short u16x8 __attribute__((ext_vector_type(8)));
typedef unsigned int u32;

union ABf { bf16x8 v; u32 d[4]; unsigned short s[8]; };

DEV unsigned short f2bf(float f) {   // RNE float->bf16, input guaranteed non-NaN
  union { float f; u32 u; } v; v.f = f;
  u32 u = v.u;
  return (unsigned short)((u + 0x7FFFu + ((u >> 16) & 1u)) >> 16);
}

DEV void gload_lds16(const void* g, void* l) {
  __builtin_amdgcn_global_load_lds(
      (__attribute__((address_space(1))) void*)(unsigned long long)(uintptr_t)g,
      (__attribute__((address_space(3))) void*)l,
      16, 0, 0);
}

// ---------------------------------------------------------------------------
// K1: per-row NaN scan. Writes bf16 x_clean, deterministic (sorted) missing
// index list per row; pad slots zero-filled (k=0) so the epilogue's vector
// kv loads read benign indices (B-side zeroing makes them no-ops).
// ---------------------------------------------------------------------------
__global__ __launch_bounds__(256) void prep_kernel(
    const float* __restrict__ x, unsigned short* __restrict__ xb,
    unsigned short* __restrict__ midx, int* __restrict__ counts) {
  const int row = blockIdx.x, t = threadIdx.x;
  __shared__ int ps[256];

  float4 v = ((const float4*)x)[row * (IN / 4) + t];  // cols 4t..4t+3
  bool n0 = (v.x != v.x), n1 = (v.y != v.y), n2 = (v.z != v.z), n3 = (v.w != v.w);

  ushort4 o;
  o.x = f2bf(n0 ? 0.f : v.x);
  o.y = f2bf(n1 ? 0.f : v.y);
  o.z = f2bf(n2 ? 0.f : v.z);
  o.w = f2bf(n3 ? 0.f : v.w);
  ((ushort4*)xb)[row * (IN / 4) + t] = o;

  int lc = (int)n0 + (int)n1 + (int)n2 + (int)n3;
  ps[t] = lc;
  __syncthreads();
  for (int off = 1; off < 256; off <<= 1) {
    int add = (t >= off) ? ps[t - off] : 0;
    __syncthreads();
    ps[t] += add;
    __syncthreads();
  }
  int pos = ps[t] - lc;  // exclusive prefix
  int col = 4 * t;
  if (n0) { if (pos < MAXM) midx[row * MAXM + pos] = (unsigned short)(col + 0); pos++; }
  if (n1) { if (pos < MAXM) midx[row * MAXM + pos] = (unsigned short)(col + 1); pos++; }
  if (n2) { if (pos < MAXM) midx[row * MAXM + pos] = (unsigned short)(col + 2); pos++; }
  if (n3) { if (pos < MAXM) midx[row * MAXM + pos] = (unsigned short)(col + 3); pos++; }
  if (t == 255) counts[row] = min(ps[255], MAXM);
  __syncthreads();
  int mm = min(ps[255], MAXM);
  for (int idx = mm + t; idx < MAXM; idx += 256) midx[row * MAXM + idx] = 0;
}

// ---------------------------------------------------------------------------
// K1b: W [IN][OUT] f32 -> Wt [OUT][IN] bf16 (B^T layout for the MFMA GEMM).
// Block (0,0) additionally computes softmax(gw) -> p_ws[8] (row-independent).
// ---------------------------------------------------------------------------
__global__ __launch_bounds__(256) void transpose_w(
    const float* __restrict__ W, unsigned short* __restrict__ Wt,
    const float* __restrict__ gw, float* __restrict__ p_ws) {
  __shared__ float tile[32][33];
  const int k0 = blockIdx.x * 32, n0 = blockIdx.y * 32;
  const int tx = threadIdx.x, ty = threadIdx.y;

  if (k0 == 0 && n0 == 0 && tx == 0 && ty == 0) {
    float wmax = -1e30f;
    for (int i = 0; i < NC; ++i) wmax = fmaxf(wmax, gw[i]);
    float e[NC], s = 0.f;
    for (int i = 0; i < NC; ++i) { e[i] = expf(gw[i] - wmax); s += e[i]; }
    for (int i = 0; i < NC; ++i) p_ws[i] = e[i] / s;
  }

  for (int r = ty; r < 32; r += 8) tile[r][tx] = W[(k0 + r) * OUT + (n0 + tx)];
  __syncthreads();
  for (int r = ty; r < 32; r += 8) Wt[(n0 + r) * IN + (k0 + tx)] = f2bf(tile[tx][r]);
}

// ---------------------------------------------------------------------------
// K2: base = xb @ Wt^T. 128x128 tile, BK=32, 4 waves, global_load_lds
// staging (m97 structure). Unchanged since R1.
// ---------------------------------------------------------------------------
__global__ __launch_bounds__(256) void gemm_base(
    const unsigned short* __restrict__ A, const unsigned short* __restrict__ Bt,
    float* __restrict__ C, int M) {
  __shared__ __align__(16) unsigned short sA[128 * 32];
  __shared__ __align__(16) unsigned short sB[128 * 32];

  const int t = threadIdx.x;
  const int lane = t & 63, w = t >> 6;
  const int wm = w >> 1, wn = w & 1;
  const int l15 = lane & 15, kblk = lane >> 4;
  const int row0 = blockIdx.x * 128, col0 = blockIdx.y * 128;

  const int r_a  = t >> 2;
  const int cb_a = (t & 3) * 8;

  f32x4 acc[4][4] = {};

  const int aoff = (wm * 64 + l15) * 32 + kblk * 8;
  const int boff = (wn * 64 + l15) * 32 + kblk * 8;

  for (int k0 = 0; k0 < IN; k0 += 32) {
    __syncthreads();
    gload_lds16(&A[(size_t)(row0 + r_a) * IN + k0 + cb_a],       &sA[t * 8]);
    gload_lds16(&A[(size_t)(row0 + r_a + 64) * IN + k0 + cb_a],  &sA[2048 + t * 8]);
    gload_lds16(&Bt[(size_t)(col0 + r_a) * IN + k0 + cb_a],      &sB[t * 8]);
    gload_lds16(&Bt[(size_t)(col0 + r_a + 64) * IN + k0 + cb_a], &sB[2048 + t * 8]);
    __syncthreads();

    bf16x8 af[4], bfr[4];
#pragma unroll
    for (int mi = 0; mi < 4; ++mi) af[mi]  = *(const bf16x8*)&sA[aoff + mi * 16 * 32];
#pragma unroll
    for (int ni = 0; ni < 4; ++ni) bfr[ni] = *(const bf16x8*)&sB[boff + ni * 16 * 32];
#pragma unroll
    for (int mi = 0; mi < 4; ++mi)
#pragma unroll
      for (int ni = 0; ni < 4; ++ni)
        acc[mi][ni] = __builtin_amdgcn_mfma_f32_16x16x32_bf16(af[mi], bfr[ni], acc[mi][ni], 0, 0, 0);
  }

#pragma unroll
  for (int mi = 0; mi < 4; ++mi)
#pragma unroll
    for (int ni = 0; ni < 4; ++ni) {
      int grow = row0 + wm * 64 + mi * 16 + kblk * 4;
      int gcol = col0 + wn * 64 + ni * 16 + l15;
#pragma unroll
      for (int r = 0; r < 4; ++r)
        C[(size_t)(grow + r) * OUT + gcol] = acc[mi][ni][r];
    }
}

// ---------------------------------------------------------------------------
// K3 (MFMA v6 = R13's verified kernel with BATCHED latency): the only change
// vs R13 (164us, both pipes idle -> per-tile load-latency serialization) is
// the A-pipeline: ALL 64 A-values (8 tiles x 8 slots) are loaded in ONE burst
// together with the B-phase loads (~72 VMEM in flight per lane), so the ~300
// cyc L2 latency is paid once per chunk instead of 8x. Compute phase then
// runs uninterrupted (pack + 16 MFMA + readout). All indices compile-time
// (rule #20: no scratch). nch=1 for ~99.4% of rows.
// ---------------------------------------------------------------------------
__global__ __launch_bounds__(256) void epilogue_mfma6(
    float* __restrict__ io, const float* __restrict__ W,
    const float* __restrict__ bvec, const float* __restrict__ p_ws,
    const float* __restrict__ gmean, const float* __restrict__ gcov,
    const unsigned short* __restrict__ midx, const int* __restrict__ counts) {
  const int row = blockIdx.x;
  const int cb  = blockIdx.y * 512;
  const int t   = threadIdx.x;
  const int lane = t & 63, wvi = t >> 6;
  const int nn = lane & 15, ii = lane & 7, g = lane >> 4;
  const bool isCov = nn >= 8;

  const int m = counts[row];

  if (m == 0) {  // full row: relu (uniform; essentially never taken at 2% miss)
    int c = cb + 2 * t;
    f32x2 bb = *(const f32x2*)(io + (size_t)row * OUT + c);
    f32x2 bi = *(const f32x2*)(bvec + c);
    f32x2 r; r[0] = fmaxf(bb[0] + bi[0], 0.f); r[1] = fmaxf(bb[1] + bi[1], 0.f);
    *(f32x2*)(io + (size_t)row * OUT + c) = r;
    return;
  }

  const int nch = (m + 31) >> 5;
  const unsigned short* mrow = midx + (size_t)row * MAXM;

  const unsigned colA = (unsigned)(cb + wvi * 128 + nn);  // lane's col (+16/tile)
  const float* gsrc = (isCov ? gcov : gmean) + ii * IN;   // comp source row

  f32x4 acc[8] = {};

  for (int ch = 0; ch < nch; ++ch) {
    // lane's 8 k-slots: one 16B load (pad region zero-filled by prep)
    u16x8 kvv = *(const u16x8*)&mrow[ch * 32 + g * 8];

    unsigned aoff[8];
#pragma unroll
    for (int j = 0; j < 8; ++j) aoff[j] = ((unsigned)kvv[j] << 10) + colA;

    // ---- issue B loads (8) ----
    float bv[8];
#pragma unroll
    for (int j = 0; j < 8; ++j) bv[j] = gsrc[kvv[j]];

    // ---- issue ALL A loads (64, one burst; latency paid once) ----
    float av[8][8];
#pragma unroll
    for (int tl = 0; tl < 8; ++tl)
#pragma unroll
      for (int j = 0; j < 8; ++j) av[tl][j] = W[aoff[j] + tl * 16];

    // ---- B fragment: (mean | |cov|) for comp ii, slots g*8..g*8+7 ----
#pragma unroll
    for (int j = 0; j < 8; ++j) {
      float v = bv[j];
      if (isCov) v = fabsf(v);
      bv[j] = (ch * 32 + g * 8 + j < m) ? v : 0.f;       // zero padded slots
    }
    ABf vals;
#pragma unroll
    for (int j = 0; j < 4; ++j)
      asm("v_cvt_pk_bf16_f32 %0, %1, %2" : "=v"(vals.d[j]) : "v"(bv[2*j]), "v"(bv[2*j+1]));
    ABf zf; zf.d[0] = zf.d[1] = zf.d[2] = zf.d[3] = 0;
    bf16x8 bm = isCov ? zf.v : vals.v;   // mean half (N-cols 0..7)
    bf16x8 bc = isCov ? vals.v : zf.v;   // cov  half (N-cols 8..15)

    // ---- compute phase: pack + 2 MFMAs per tile, no loads interleaved ----
#pragma unroll
    for (int tl = 0; tl < 8; ++tl) {
      ABf aw, a2;
#pragma unroll
      for (int p = 0; p < 4; ++p) {
        asm("v_cvt_pk_bf16_f32 %0, %1, %2" : "=v"(aw.d[p]) : "v"(av[tl][2*p]), "v"(av[tl][2*p+1]));
        float q0 = av[tl][2*p] * av[tl][2*p], q1 = av[tl][2*p+1] * av[tl][2*p+1];
        asm("v_cvt_pk_bf16_f32 %0, %1, %2" : "=v"(a2.d[p]) : "v"(q0), "v"(q1));
      }
      acc[tl] = __builtin_amdgcn_mfma_f32_16x16x32_bf16(aw.v, bm, acc[tl], 0, 0, 0);
      acc[tl] = __builtin_amdgcn_mfma_f32_16x16x32_bf16(a2.v, bc, acc[tl], 0, 0, 0);
    }
  }

  // ---- nr() epilogue (R9/R13-verified readout) ----
  const float INV_SQRT_2PI = 0.39894228040143268f;
  const float LOGI_K = 1.702f;
  const float L2E = 1.442695040888963f;
  const float pi_w = p_ws[ii];
  const int rrb = isCov ? 2 : 0;

#pragma unroll
  for (int tl = 0; tl < 8; ++tl) {
    f32x4 ac = acc[tl];
    float s0 = __shfl_xor(ac[0], 8);
    float s1 = __shfl_xor(ac[1], 8);
    float s2 = __shfl_xor(ac[2], 8);
    float s3 = __shfl_xor(ac[3], 8);
    float A0 = isCov ? s2 : ac[0];
    float A1 = isCov ? s3 : ac[1];
    float V0 = isCov ? ac[2] : s0;
    float V1 = isCov ? ac[3] : s1;

    int c = cb + wvi * 128 + tl * 16 + g * 4 + rrb;
    f32x2 bb = *(const f32x2*)(io + (size_t)row * OUT + c);
    f32x2 bi = *(const f32x2*)(bvec + c);

    float t0, t1;
    {
      float a   = bb[0] + bi[0] + A0;
      float rs  = (V0 > 0.f) ? __builtin_amdgcn_rsqf(V0) : 1.0f;
      float z   = a * rs;
      float eu  = __builtin_amdgcn_exp2f(-0.5f * L2E * z * z);
      float el  = __builtin_amdgcn_exp2f(-LOGI_K * L2E * z);
      float Phi = __builtin_amdgcn_rcpf(1.0f + el);
      t0 = pi_w * fmaf(z, Phi, INV_SQRT_2PI * eu);
    }
    {
      float a   = bb[1] + bi[1] + A1;
      float rs  = (V1 > 0.f) ? __builtin_amdgcn_rsqf(V1) : 1.0f;
      float z   = a * rs;
      float eu  = __builtin_amdgcn_exp2f(-0.5f * L2E * z * z);
      float el  = __builtin_amdgcn_exp2f(-LOGI_K * L2E * z);
      float Phi = __builtin_amdgcn_rcpf(1.0f + el);
      t1 = pi_w * fmaf(z, Phi, INV_SQRT_2PI * eu);
    }
#pragma unroll
    for (int d = 1; d <= 4; d <<= 1) {
      t0 += __shfl_xor(t0, d);
      t1 += __shfl_xor(t1, d);
    }
    if (ii == 0) {
      f32x2 o; o[0] = t0; o[1] = t1;
      *(f32x2*)(io + (size_t)row * OUT + c) = o;
    }
  }
}

// ---------------------------------------------------------------------------
extern "C" void kernel_launch(void* const* d_in, const int* in_sizes, int n_in,
                              void* d_out, int out_size, void* d_ws, size_t ws_size,
                              hipStream_t stream) {
  const float* x  = (const float*)d_in[0];
  const float* W  = (const float*)d_in[1];
  const float* b  = (const float*)d_in[2];
  const float* gw = (const float*)d_in[3];
  const float* gm = (const float*)d_in[4];
  const float* gc = (const float*)d_in[5];
  float* out = (float*)d_out;
  const int M = in_sizes[0] / IN;  // 8192

  // workspace layout (R9-proven footprint, ~19.5 MB)
  char* ws = (char*)d_ws;
  size_t off = 0;
  unsigned short* xb   = (unsigned short*)(ws + off); off += (size_t)M * IN * 2;     // 16 MB
  unsigned short* Wt   = (unsigned short*)(ws + off); off += (size_t)IN * OUT * 2;   //  2 MB
  unsigned short* midx = (unsigned short*)(ws + off); off += (size_t)M * MAXM * 2;   // 1.5 MB
  int* counts          = (int*)(ws + off);            off += (size_t)M * 4;          // 32 KB
  float* p_ws          = (float*)(ws + off);          off += 256;

  prep_kernel<<<M, 256, 0, stream>>>(x, xb, midx, counts);
  transpose_w<<<dim3(IN / 32, OUT / 32), dim3(32, 8), 0, stream>>>(W, Wt, gw, p_ws);
  gemm_base<<<dim3(M / 128, OUT / 128), 256, 0, stream>>>(xb, Wt, out, M);
  epilogue_mfma6<<<dim3(M, 2), 256, 0, stream>>>(out, W, b, p_ws, gm, gc, midx, counts);
}